// Round 1
// baseline (769.745 us; speedup 1.0000x reference)
//
#include <hip/hip_runtime.h>
#include <hip/hip_bf16.h>

// Problem constants
#define TB 2
#define TS 2048
#define TD 1024
#define TH 16
#define THD 64
#define TE 8
#define TKK 2
#define TF 4096
#define TT (TB*TS)      // 4096 tokens
#define QLD (3*TD)      // 3072

typedef unsigned short u16;
typedef __attribute__((ext_vector_type(8))) __bf16 bf16x8;
typedef __attribute__((ext_vector_type(8))) u16 u16x8;
typedef __attribute__((ext_vector_type(4))) u16 u16x4;
typedef __attribute__((ext_vector_type(4))) float f32x4;

static __device__ __forceinline__ u16 f2bf(float f){
  __hip_bfloat16 h = __float2bfloat16(f);
  return __builtin_bit_cast(u16, h);
}

#define MFMA16(a,b,c) __builtin_amdgcn_mfma_f32_16x16x32_bf16((a),(b),(c),0,0,0)
#define GLL16(g, l) __builtin_amdgcn_global_load_lds( \
    (const __attribute__((address_space(1))) unsigned int*)(g), \
    (__attribute__((address_space(3))) unsigned int*)(l), 16, 0, 0)

// ---------------------------------------------------------------- utilities
__global__ __launch_bounds__(256)
void cast_bf_kernel(const float* __restrict__ in, u16* __restrict__ out, int n4){
  int i = blockIdx.x*256 + threadIdx.x;
  if (i < n4){
    float4 v = ((const float4*)in)[i];
    u16x4 o = { f2bf(v.x), f2bf(v.y), f2bf(v.z), f2bf(v.w) };
    ((u16x4*)out)[i] = o;
  }
}

// out[z][c][r] = (bf16) in[z][r][c]   (R,C multiples of 32)
__global__ __launch_bounds__(256)
void transpose_cast_kernel(const float* __restrict__ in, u16* __restrict__ out, int R, int C){
  __shared__ float tile[32][33];
  const size_t mo = (size_t)blockIdx.z * R * C;
  const float* ip = in + mo;
  u16* op = out + mo;
  const int c0 = blockIdx.x*32, r0 = blockIdx.y*32;
  const int lx = threadIdx.x & 31, ly = threadIdx.x >> 5;   // 32 x 8
#pragma unroll
  for (int i2 = 0; i2 < 4; ++i2)
    tile[ly + i2*8][lx] = ip[(size_t)(r0 + ly + i2*8)*C + c0 + lx];
  __syncthreads();
#pragma unroll
  for (int i2 = 0; i2 < 4; ++i2)
    op[(size_t)(c0 + ly + i2*8)*R + r0 + lx] = f2bf(tile[lx][ly + i2*8]);
}

__global__ void zero_counts_kernel(int* counts){
  if (threadIdx.x < TE) counts[threadIdx.x] = 0;
}

// ---------------------------------------------------------------- layernorm 1
__global__ __launch_bounds__(256)
void ln1_kernel(const float* __restrict__ x, const float* __restrict__ g,
                const float* __restrict__ bb, u16* __restrict__ h){
  const int t = blockIdx.x, tid = threadIdx.x;
  const float4 v = ((const float4*)(x + (size_t)t*TD))[tid];
  float s  = v.x + v.y + v.z + v.w;
  float ss = v.x*v.x + v.y*v.y + v.z*v.z + v.w*v.w;
#pragma unroll
  for (int d = 32; d >= 1; d >>= 1){ s += __shfl_down(s, d); ss += __shfl_down(ss, d); }
  __shared__ float red[8];
  const int lane = tid & 63, wave = tid >> 6;
  if (lane == 0){ red[wave] = s; red[4+wave] = ss; }
  __syncthreads();
  const float S  = red[0]+red[1]+red[2]+red[3];
  const float SS = red[4]+red[5]+red[6]+red[7];
  const float mu = S * (1.f/TD);
  const float rstd = rsqrtf(SS*(1.f/TD) - mu*mu + 1e-5f);
  const float4 gv = ((const float4*)g)[tid];
  const float4 bv = ((const float4*)bb)[tid];
  u16x4 o = { f2bf((v.x-mu)*rstd*gv.x + bv.x),
              f2bf((v.y-mu)*rstd*gv.y + bv.y),
              f2bf((v.z-mu)*rstd*gv.z + bv.z),
              f2bf((v.w-mu)*rstd*gv.w + bv.w) };
  ((u16x4*)(h + (size_t)t*TD))[tid] = o;
}

// ------------------------------------------------- layernorm 2 + fp32 router
__global__ __launch_bounds__(256)
void ln2_router_kernel(const float* __restrict__ xo, const float* __restrict__ g,
                       const float* __restrict__ bb, u16* __restrict__ h2,
                       const float* __restrict__ rw, const float* __restrict__ rb,
                       int* __restrict__ counts, int* __restrict__ topidx,
                       float* __restrict__ topw){
  const int t = blockIdx.x, tid = threadIdx.x;
  const float4 v = ((const float4*)(xo + (size_t)t*TD))[tid];
  float s  = v.x + v.y + v.z + v.w;
  float ss = v.x*v.x + v.y*v.y + v.z*v.z + v.w*v.w;
#pragma unroll
  for (int d = 32; d >= 1; d >>= 1){ s += __shfl_down(s, d); ss += __shfl_down(ss, d); }
  __shared__ float red[8];
  const int lane = tid & 63, wave = tid >> 6;
  if (lane == 0){ red[wave] = s; red[4+wave] = ss; }
  __syncthreads();
  const float S  = red[0]+red[1]+red[2]+red[3];
  const float SS = red[4]+red[5]+red[6]+red[7];
  const float mu = S * (1.f/TD);
  const float rstd = rsqrtf(SS*(1.f/TD) - mu*mu + 1e-5f);
  const float4 gv = ((const float4*)g)[tid];
  const float4 bv = ((const float4*)bb)[tid];
  float hv[4] = { (v.x-mu)*rstd*gv.x + bv.x, (v.y-mu)*rstd*gv.y + bv.y,
                  (v.z-mu)*rstd*gv.z + bv.z, (v.w-mu)*rstd*gv.w + bv.w };
  u16x4 o = { f2bf(hv[0]), f2bf(hv[1]), f2bf(hv[2]), f2bf(hv[3]) };
  ((u16x4*)(h2 + (size_t)t*TD))[tid] = o;

  // fp32 router logits (top-k is discrete: keep full precision)
  float acc[TE] = {0,0,0,0,0,0,0,0};
#pragma unroll
  for (int q = 0; q < 4; ++q){
    const int d = tid*4 + q;
    const float4 r0 = ((const float4*)(rw + (size_t)d*TE))[0];
    const float4 r1 = ((const float4*)(rw + (size_t)d*TE))[1];
    acc[0] += hv[q]*r0.x; acc[1] += hv[q]*r0.y; acc[2] += hv[q]*r0.z; acc[3] += hv[q]*r0.w;
    acc[4] += hv[q]*r1.x; acc[5] += hv[q]*r1.y; acc[6] += hv[q]*r1.z; acc[7] += hv[q]*r1.w;
  }
#pragma unroll
  for (int d = 32; d >= 1; d >>= 1)
#pragma unroll
    for (int e = 0; e < TE; ++e) acc[e] += __shfl_down(acc[e], d);
  __shared__ float racc[4][TE];
  if (lane == 0)
#pragma unroll
    for (int e = 0; e < TE; ++e) racc[wave][e] = acc[e];
  __syncthreads();
  if (tid == 0){
    float lg[TE];
#pragma unroll
    for (int e = 0; e < TE; ++e)
      lg[e] = racc[0][e] + racc[1][e] + racc[2][e] + racc[3][e] + rb[e];
    int e1 = 0;
    for (int e = 1; e < TE; ++e) if (lg[e] > lg[e1]) e1 = e;
    int e2 = -1;
    for (int e = 0; e < TE; ++e){ if (e == e1) continue; if (e2 < 0 || lg[e] > lg[e2]) e2 = e; }
    const float w1 = 1.f / (1.f + __expf(lg[e2] - lg[e1]));
    const float w2 = 1.f / (1.f + __expf(lg[e1] - lg[e2]));
    topidx[t*2]   = e1;  topidx[t*2+1] = e2;
    topw[t*2]     = w1;  topw[t*2+1]   = w2;
    atomicAdd(&counts[e1], 1);
    atomicAdd(&counts[e2], 1);
  }
}

__global__ void offsets_kernel(const int* __restrict__ counts, int* __restrict__ offs,
                               int* __restrict__ cursors, float* __restrict__ load_out){
  if (threadIdx.x == 0){
    int off = 0;
    for (int e = 0; e < TE; ++e){
      offs[e] = off; cursors[e] = off; off += counts[e];
      load_out[e] = (float)counts[e];
    }
  }
}

__global__ __launch_bounds__(256)
void scatter_kernel(const int* __restrict__ topidx, const float* __restrict__ topw,
                    int* __restrict__ cursors, int* __restrict__ assign_tok,
                    float* __restrict__ assign_w, int* __restrict__ token_slot){
  const int t = blockIdx.x*256 + threadIdx.x;
  if (t >= TT) return;
#pragma unroll
  for (int k = 0; k < 2; ++k){
    const int e = topidx[t*2 + k];
    const int pos = atomicAdd(&cursors[e], 1);
    assign_tok[pos] = t;
    assign_w[pos]   = topw[t*2 + k];
    token_slot[t*2 + k] = pos;
  }
}

// ---------------------------------------------------------------- GEMM core
// C[128,128] tile = A[M,K](bf16, row-major) x Bt[N,K](bf16, row-major) per block.
// 4 waves, each 64x64 (4x4 frags of 16x16x32), BK=32, double-buffered LDS,
// global_load_lds width 16.
// MODE 0: QKV   : out_bf = acc + bias            (ld = 3*TD)
// MODE 1: OPROJ : out_f  = acc + bias + resid    (ld = TD)
// MODE 2: MOE1  : A rows gathered by assign_tok; out_bf = gelu(acc + b1[e])  (ld = TF)
// MODE 3: MOE2  : A rows = hidden slots; out_f = (acc + b2[e]) * assign_w    (ld = TD)
template<int MODE>
__global__ __launch_bounds__(256)
void gemm_bt(const u16* __restrict__ A, const u16* __restrict__ Bt,
             const float* __restrict__ bias, const float* __restrict__ resid,
             float* __restrict__ outF, u16* __restrict__ outB,
             int K, int N,
             const int* __restrict__ counts, const int* __restrict__ offs,
             const int* __restrict__ assign_tok, const float* __restrict__ assign_w)
{
  __shared__ u16 As[2][128*32];
  __shared__ u16 Bs[2][128*32];
  const int tid = threadIdx.x;
  const int n0  = blockIdx.x * 128;
  int row0 = 0, slotbase = 0, cntRem = 128, slotEnd = 0;
  if (MODE == 0 || MODE == 1){
    row0 = blockIdx.y * 128;
  } else {
    const int e  = blockIdx.y >> 5;
    const int mt = blockIdx.y & 31;
    const int cnt = counts[e];
    if (mt*128 >= cnt) return;
    slotbase = offs[e] + mt*128;
    slotEnd  = offs[e] + cnt;
    cntRem   = cnt - mt*128; if (cntRem > 128) cntRem = 128;
    Bt   += (size_t)e * K * N;
    bias += (size_t)e * N;
  }
  // staging pointers (per thread: 2 x 16B for A, 2 x 16B for B per K-step)
  const int srow = tid >> 2, skseg = tid & 3;
  const u16* aptr[2];
  const u16* bptr[2];
#pragma unroll
  for (int it = 0; it < 2; ++it){
    const int r = it*64 + srow;
    if (MODE == 0 || MODE == 1){
      aptr[it] = A + (size_t)(row0 + r)*K + skseg*8;
    } else if (MODE == 2){
      int slot = slotbase + r; if (slot > slotEnd-1) slot = slotEnd-1;
      aptr[it] = A + (size_t)assign_tok[slot]*K + skseg*8;
    } else {
      int slot = slotbase + r; if (slot > slotEnd-1) slot = slotEnd-1;
      aptr[it] = A + (size_t)slot*K + skseg*8;
    }
    bptr[it] = Bt + (size_t)(n0 + it*64 + srow)*K + skseg*8;
  }

#define STAGE(buf, kt) do {                                        \
    _Pragma("unroll")                                              \
    for (int it = 0; it < 2; ++it){                                \
      GLL16(aptr[it] + (size_t)(kt)*32, &As[buf][it*2048 + tid*8]);\
      GLL16(bptr[it] + (size_t)(kt)*32, &Bs[buf][it*2048 + tid*8]);\
    } } while(0)

  const int lane = tid & 63, wave = tid >> 6;
  const int wm = (wave >> 1) * 64, wn = (wave & 1) * 64;
  const int r16 = lane & 15, kgr = lane >> 4;
  const f32x4 z4 = {0.f,0.f,0.f,0.f};
  f32x4 acc[4][4];
#pragma unroll
  for (int i = 0; i < 4; ++i)
#pragma unroll
    for (int j = 0; j < 4; ++j) acc[i][j] = z4;

  STAGE(0, 0);
  __syncthreads();
  const int nk = K >> 5;
  for (int kt = 0; kt < nk; ++kt){
    const int cur = kt & 1;
    if (kt + 1 < nk) STAGE(cur ^ 1, kt + 1);
    bf16x8 a[4], b[4];
#pragma unroll
    for (int i = 0; i < 4; ++i)
      a[i] = *(const bf16x8*)&As[cur][(wm + i*16 + r16)*32 + kgr*8];
#pragma unroll
    for (int j = 0; j < 4; ++j)
      b[j] = *(const bf16x8*)&Bs[cur][(wn + j*16 + r16)*32 + kgr*8];
#pragma unroll
    for (int i = 0; i < 4; ++i)
#pragma unroll
      for (int j = 0; j < 4; ++j)
        acc[i][j] = MFMA16(a[i], b[j], acc[i][j]);
    __syncthreads();
  }
#undef STAGE

  // epilogue: C frag mapping col=lane&15, row=(lane>>4)*4+reg  [m89-verified]
#pragma unroll
  for (int i = 0; i < 4; ++i){
#pragma unroll
    for (int r = 0; r < 4; ++r){
      const int row = wm + i*16 + kgr*4 + r;
#pragma unroll
      for (int j = 0; j < 4; ++j){
        const int col = n0 + wn + j*16 + r16;
        float v = acc[i][j][r];
        if (MODE == 0){
          v += bias[col];
          outB[(size_t)(row0 + row)*QLD + col] = f2bf(v);
        } else if (MODE == 1){
          const size_t idx = (size_t)(row0 + row)*TD + col;
          outF[idx] = v + bias[col] + resid[idx];
        } else if (MODE == 2){
          if (row < cntRem){
            v += bias[col];
            const float t = tanhf(0.7978845608028654f * (v + 0.044715f*v*v*v));
            outB[(size_t)(slotbase + row)*TF + col] = f2bf(0.5f*v*(1.f + t));
          }
        } else {
          if (row < cntRem){
            outF[(size_t)(slotbase + row)*TD + col] =
                (v + bias[col]) * assign_w[slotbase + row];
          }
        }
      }
    }
  }
}

// ------------------------------------------------------- flash attention
// grid = TB*TH*(TS/64); block 256 = 4 waves; wave w owns 16 q-rows.
__global__ __launch_bounds__(256)
void attn_kernel(const u16* __restrict__ qkv, u16* __restrict__ ctx){
  const int blk = blockIdx.x;
  const int qt = blk & 31, bh = blk >> 5;
  const int b = bh >> 4, h = bh & 15;
  const int tid = threadIdx.x, lane = tid & 63, wave = tid >> 6;
  const int r16 = lane & 15, kgr = lane >> 4;
  const size_t base = (size_t)b * TS * QLD;
  const u16* Q  = qkv + base + h*THD;
  const u16* Kp = qkv + base + TD + h*THD;
  const u16* Vp = qkv + base + 2*TD + h*THD;
  const int q0 = qt*64;
  const int qw = q0 + wave*16;

  bf16x8 qa[2];
#pragma unroll
  for (int kbl = 0; kbl < 2; ++kbl)
    qa[kbl] = *(const bf16x8*)&Q[(size_t)(qw + r16)*QLD + kbl*32 + kgr*8];

  const f32x4 z4 = {0.f,0.f,0.f,0.f};
  f32x4 O[4] = { z4, z4, z4, z4 };
  float m_r[4] = { -1e30f, -1e30f, -1e30f, -1e30f };
  float l_r[4] = { 0.f, 0.f, 0.f, 0.f };

  __shared__ u16 VT[64][72];        // V transposed [hd][kv], +8 pad
  __shared__ u16 Plds[4][16][72];   // per-wave P tile [q][kv], +8 pad

  for (int kt = 0; kt <= qt; ++kt){
    const int kv0 = kt*64;
    __syncthreads();   // previous tile's VT reads done
    // stage V transposed: 2 x (8 contiguous hd) per thread
#pragma unroll
    for (int it = 0; it < 2; ++it){
      const int c = tid + it*256;
      const int kvr = c >> 3, hs = c & 7;
      u16x8 vv = *(const u16x8*)&Vp[(size_t)(kv0 + kvr)*QLD + hs*8];
#pragma unroll
      for (int jj = 0; jj < 8; ++jj) VT[hs*8 + jj][kvr] = vv[jj];
    }
    __syncthreads();

    // S = Q K^T (scaled later)
    f32x4 s[4];
#pragma unroll
    for (int j = 0; j < 4; ++j){
      const bf16x8 k0 = *(const bf16x8*)&Kp[(size_t)(kv0 + j*16 + r16)*QLD + kgr*8];
      const bf16x8 k1 = *(const bf16x8*)&Kp[(size_t)(kv0 + j*16 + r16)*QLD + 32 + kgr*8];
      s[j] = MFMA16(qa[0], k0, z4);
      s[j] = MFMA16(qa[1], k1, s[j]);
    }
    const bool diag = (kt == qt);
    float mx[4] = { -3e38f, -3e38f, -3e38f, -3e38f };
#pragma unroll
    for (int j = 0; j < 4; ++j)
#pragma unroll
      for (int r = 0; r < 4; ++r){
        float v = s[j][r] * 0.125f;
        if (diag && (kv0 + j*16 + r16 > qw + kgr*4 + r)) v += -1e9f;
        s[j][r] = v;
        mx[r] = fmaxf(mx[r], v);
      }
#pragma unroll
    for (int d = 1; d < 16; d <<= 1)
#pragma unroll
      for (int r = 0; r < 4; ++r) mx[r] = fmaxf(mx[r], __shfl_xor(mx[r], d));
    float al[4];
#pragma unroll
    for (int r = 0; r < 4; ++r){
      const float mn = fmaxf(m_r[r], mx[r]);
      al[r] = __expf(m_r[r] - mn);
      m_r[r] = mn;
    }
    float rs[4] = {0.f,0.f,0.f,0.f};
#pragma unroll
    for (int j = 0; j < 4; ++j)
#pragma unroll
      for (int r = 0; r < 4; ++r){
        const float p = __expf(s[j][r] - m_r[r]);
        s[j][r] = p;
        rs[r] += p;
      }
#pragma unroll
    for (int d = 1; d < 16; d <<= 1)
#pragma unroll
      for (int r = 0; r < 4; ++r) rs[r] += __shfl_xor(rs[r], d);
#pragma unroll
    for (int r = 0; r < 4; ++r) l_r[r] = l_r[r]*al[r] + rs[r];
#pragma unroll
    for (int c = 0; c < 4; ++c)
#pragma unroll
      for (int r = 0; r < 4; ++r) O[c][r] *= al[r];
    // P -> LDS (transpose C-layout -> A-layout)
#pragma unroll
    for (int j = 0; j < 4; ++j)
#pragma unroll
      for (int r = 0; r < 4; ++r)
        Plds[wave][kgr*4 + r][j*16 + r16] = f2bf(s[j][r]);
    // O += P V
#pragma unroll
    for (int kbl = 0; kbl < 2; ++kbl){
      const bf16x8 pa = *(const bf16x8*)&Plds[wave][r16][kbl*32 + kgr*8];
#pragma unroll
      for (int c = 0; c < 4; ++c){
        const bf16x8 vb = *(const bf16x8*)&VT[c*16 + r16][kbl*32 + kgr*8];
        O[c] = MFMA16(pa, vb, O[c]);
      }
    }
  }
  u16* cp = ctx + (size_t)b*TS*TD + h*THD;
#pragma unroll
  for (int r = 0; r < 4; ++r){
    const float inv = 1.f / l_r[r];
    const int qrow = qw + kgr*4 + r;
#pragma unroll
    for (int c = 0; c < 4; ++c)
      cp[(size_t)qrow*TD + c*16 + r16] = f2bf(O[c][r] * inv);
  }
}

// ---------------------------------------------------------------- combine
__global__ __launch_bounds__(256)
void combine_kernel(float* __restrict__ out, const float* __restrict__ slot_out,
                    const int* __restrict__ token_slot){
  const int i = blockIdx.x*256 + threadIdx.x;   // over TT*TD/4
  const int t = i >> 8, c = i & 255;
  const int s0 = token_slot[t*2], s1 = token_slot[t*2+1];
  const float4 a = ((const float4*)out)[i];
  const float4 u = ((const float4*)slot_out)[(size_t)s0*256 + c];
  const float4 w = ((const float4*)slot_out)[(size_t)s1*256 + c];
  float4 o = { a.x+u.x+w.x, a.y+u.y+w.y, a.z+u.z+w.z, a.w+u.w+w.w };
  ((float4*)out)[i] = o;
}

// ---------------------------------------------------------------- launcher
extern "C" void kernel_launch(void* const* d_in, const int* in_sizes, int n_in,
                              void* d_out, int out_size, void* d_ws, size_t ws_size,
                              hipStream_t stream){
  const float* x     = (const float*)d_in[0];
  // d_in[1] = attn_mask (causal; implemented analytically)
  const float* ln1_g = (const float*)d_in[2];
  const float* ln1_b = (const float*)d_in[3];
  const float* w_qkv = (const float*)d_in[4];
  const float* b_qkv = (const float*)d_in[5];
  const float* w_o   = (const float*)d_in[6];
  const float* b_o   = (const float*)d_in[7];
  const float* ln2_g = (const float*)d_in[8];
  const float* ln2_b = (const float*)d_in[9];
  const float* rw    = (const float*)d_in[10];
  const float* rb    = (const float*)d_in[11];
  const float* w1    = (const float*)d_in[12];
  const float* b1    = (const float*)d_in[13];
  const float* w2    = (const float*)d_in[14];
  const float* b2    = (const float*)d_in[15];
  float* out = (float*)d_out;

  // workspace arena (~263 MB)
  char* wsp = (char*)d_ws;
  size_t off = 0;
  auto alloc = [&](size_t bytes)->void*{
    void* p = wsp + off; off += (bytes + 255) & ~(size_t)255; return p;
  };
  u16* wqkv_bf = (u16*)alloc((size_t)3*TD*TD*2);
  u16* wo_bf   = (u16*)alloc((size_t)TD*TD*2);
  u16* w1t     = (u16*)alloc((size_t)TE*TD*TF*2);   // [E][F][D]
  u16* w2t     = (u16*)alloc((size_t)TE*TD*TF*2);   // [E][D][F]
  u16* h2bf    = (u16*)alloc((size_t)TT*TD*2);
  u16* hidden  = (u16*)alloc((size_t)TT*TKK*TF*2);  // [8192][F]
  char* ph1    = (char*)alloc((size_t)44*1024*1024); // phase-1 arena / slot_out
  u16* hbf     = (u16*)ph1;
  u16* qkvbf   = (u16*)(ph1 + (size_t)TT*TD*2);
  u16* ctxbf   = (u16*)(ph1 + (size_t)TT*TD*2 + (size_t)TT*3*TD*2);
  float* slot_out = (float*)ph1;                     // reuses dead phase-1 space
  int*   topidx     = (int*)alloc(TT*2*4);
  float* topw       = (float*)alloc(TT*2*4);
  int*   counts     = (int*)alloc(64);
  int*   offs       = (int*)alloc(64);
  int*   cursors    = (int*)alloc(64);
  int*   assign_tok = (int*)alloc(TT*TKK*4);
  float* assign_w_  = (float*)alloc(TT*TKK*4);
  int*   token_slot = (int*)alloc(TT*TKK*4);
  (void)ws_size; (void)in_sizes; (void)n_in; (void)out_size;

  const dim3 b256(256);
  zero_counts_kernel<<<dim3(1), dim3(64), 0, stream>>>(counts);
  cast_bf_kernel<<<dim3(3*TD*TD/4/256), b256, 0, stream>>>(w_qkv, wqkv_bf, 3*TD*TD/4);
  cast_bf_kernel<<<dim3(TD*TD/4/256), b256, 0, stream>>>(w_o, wo_bf, TD*TD/4);
  transpose_cast_kernel<<<dim3(TF/32, TD/32, TE), b256, 0, stream>>>(w1, w1t, TD, TF);
  transpose_cast_kernel<<<dim3(TD/32, TF/32, TE), b256, 0, stream>>>(w2, w2t, TF, TD);
  ln1_kernel<<<dim3(TT), b256, 0, stream>>>(x, ln1_g, ln1_b, hbf);
  gemm_bt<0><<<dim3(3*TD/128, TT/128), b256, 0, stream>>>(
      hbf, wqkv_bf, b_qkv, nullptr, nullptr, qkvbf, TD, 3*TD,
      nullptr, nullptr, nullptr, nullptr);
  attn_kernel<<<dim3(TB*TH*(TS/64)), b256, 0, stream>>>(qkvbf, ctxbf);
  gemm_bt<1><<<dim3(TD/128, TT/128), b256, 0, stream>>>(
      ctxbf, wo_bf, b_o, x, out, nullptr, TD, TD,
      nullptr, nullptr, nullptr, nullptr);
  ln2_router_kernel<<<dim3(TT), b256, 0, stream>>>(
      out, ln2_g, ln2_b, h2bf, rw, rb, counts, topidx, topw);
  offsets_kernel<<<dim3(1), dim3(64), 0, stream>>>(counts, offs, cursors, out + (size_t)TT*TD);
  scatter_kernel<<<dim3(TT/256), b256, 0, stream>>>(
      topidx, topw, cursors, assign_tok, assign_w_, token_slot);
  gemm_bt<2><<<dim3(TF/128, TE*32), b256, 0, stream>>>(
      h2bf, w1t, b1, nullptr, nullptr, hidden, TD, TF,
      counts, offs, assign_tok, assign_w_);
  gemm_bt<3><<<dim3(TD/128, TE*32), b256, 0, stream>>>(
      hidden, w2t, b2, nullptr, slot_out, nullptr, TF, TD,
      counts, offs, assign_tok, assign_w_);
  combine_kernel<<<dim3(TT*TD/4/256), b256, 0, stream>>>(out, slot_out, token_slot);
}

// Round 2
// 685.591 us; speedup vs baseline: 1.1227x; 1.1227x over previous
//
#include <hip/hip_runtime.h>
#include <hip/hip_bf16.h>

// Problem constants
#define TB 2
#define TS 2048
#define TD 1024
#define TH 16
#define THD 64
#define TE 8
#define TKK 2
#define TF 4096
#define TT (TB*TS)      // 4096 tokens
#define QLD (3*TD)      // 3072

typedef unsigned short u16;
typedef __attribute__((ext_vector_type(8))) __bf16 bf16x8;
typedef __attribute__((ext_vector_type(8))) u16 u16x8;
typedef __attribute__((ext_vector_type(4))) u16 u16x4;
typedef __attribute__((ext_vector_type(4))) float f32x4;

static __device__ __forceinline__ u16 f2bf(float f){
  __hip_bfloat16 h = __float2bfloat16(f);
  return __builtin_bit_cast(u16, h);
}

#define MFMA16(a,b,c) __builtin_amdgcn_mfma_f32_16x16x32_bf16((a),(b),(c),0,0,0)
#define GLL16(g, l) __builtin_amdgcn_global_load_lds( \
    (const __attribute__((address_space(1))) unsigned int*)(g), \
    (__attribute__((address_space(3))) unsigned int*)(l), 16, 0, 0)

// ---------------------------------------------------------------- utilities
__global__ __launch_bounds__(256)
void cast_bf_kernel(const float* __restrict__ in, u16* __restrict__ out, int n4){
  int i = blockIdx.x*256 + threadIdx.x;
  if (i < n4){
    float4 v = ((const float4*)in)[i];
    u16x4 o = { f2bf(v.x), f2bf(v.y), f2bf(v.z), f2bf(v.w) };
    ((u16x4*)out)[i] = o;
  }
}

// out[z][c][r] = (bf16) in[z][r][c]   (R,C multiples of 32)
__global__ __launch_bounds__(256)
void transpose_cast_kernel(const float* __restrict__ in, u16* __restrict__ out, int R, int C){
  __shared__ float tile[32][33];
  const size_t mo = (size_t)blockIdx.z * R * C;
  const float* ip = in + mo;
  u16* op = out + mo;
  const int c0 = blockIdx.x*32, r0 = blockIdx.y*32;
  const int lx = threadIdx.x & 31, ly = threadIdx.x >> 5;   // 32 x 8
#pragma unroll
  for (int i2 = 0; i2 < 4; ++i2)
    tile[ly + i2*8][lx] = ip[(size_t)(r0 + ly + i2*8)*C + c0 + lx];
  __syncthreads();
#pragma unroll
  for (int i2 = 0; i2 < 4; ++i2)
    op[(size_t)(c0 + ly + i2*8)*R + r0 + lx] = f2bf(tile[lx][ly + i2*8]);
}

__global__ void zero_counts_kernel(int* counts){
  if (threadIdx.x < TE) counts[threadIdx.x] = 0;
}

// ---------------------------------------------------------------- layernorm 1
__global__ __launch_bounds__(256)
void ln1_kernel(const float* __restrict__ x, const float* __restrict__ g,
                const float* __restrict__ bb, u16* __restrict__ h){
  const int t = blockIdx.x, tid = threadIdx.x;
  const float4 v = ((const float4*)(x + (size_t)t*TD))[tid];
  float s  = v.x + v.y + v.z + v.w;
  float ss = v.x*v.x + v.y*v.y + v.z*v.z + v.w*v.w;
#pragma unroll
  for (int d = 32; d >= 1; d >>= 1){ s += __shfl_down(s, d); ss += __shfl_down(ss, d); }
  __shared__ float red[8];
  const int lane = tid & 63, wave = tid >> 6;
  if (lane == 0){ red[wave] = s; red[4+wave] = ss; }
  __syncthreads();
  const float S  = red[0]+red[1]+red[2]+red[3];
  const float SS = red[4]+red[5]+red[6]+red[7];
  const float mu = S * (1.f/TD);
  const float rstd = rsqrtf(SS*(1.f/TD) - mu*mu + 1e-5f);
  const float4 gv = ((const float4*)g)[tid];
  const float4 bv = ((const float4*)bb)[tid];
  u16x4 o = { f2bf((v.x-mu)*rstd*gv.x + bv.x),
              f2bf((v.y-mu)*rstd*gv.y + bv.y),
              f2bf((v.z-mu)*rstd*gv.z + bv.z),
              f2bf((v.w-mu)*rstd*gv.w + bv.w) };
  ((u16x4*)(h + (size_t)t*TD))[tid] = o;
}

// ------------------------------------------------- layernorm 2 + fp32 router
__global__ __launch_bounds__(256)
void ln2_router_kernel(const float* __restrict__ xo, const float* __restrict__ g,
                       const float* __restrict__ bb, u16* __restrict__ h2,
                       const float* __restrict__ rw, const float* __restrict__ rb,
                       int* __restrict__ counts, int* __restrict__ topidx,
                       float* __restrict__ topw){
  const int t = blockIdx.x, tid = threadIdx.x;
  const float4 v = ((const float4*)(xo + (size_t)t*TD))[tid];
  float s  = v.x + v.y + v.z + v.w;
  float ss = v.x*v.x + v.y*v.y + v.z*v.z + v.w*v.w;
#pragma unroll
  for (int d = 32; d >= 1; d >>= 1){ s += __shfl_down(s, d); ss += __shfl_down(ss, d); }
  __shared__ float red[8];
  const int lane = tid & 63, wave = tid >> 6;
  if (lane == 0){ red[wave] = s; red[4+wave] = ss; }
  __syncthreads();
  const float S  = red[0]+red[1]+red[2]+red[3];
  const float SS = red[4]+red[5]+red[6]+red[7];
  const float mu = S * (1.f/TD);
  const float rstd = rsqrtf(SS*(1.f/TD) - mu*mu + 1e-5f);
  const float4 gv = ((const float4*)g)[tid];
  const float4 bv = ((const float4*)bb)[tid];
  float hv[4] = { (v.x-mu)*rstd*gv.x + bv.x, (v.y-mu)*rstd*gv.y + bv.y,
                  (v.z-mu)*rstd*gv.z + bv.z, (v.w-mu)*rstd*gv.w + bv.w };
  u16x4 o = { f2bf(hv[0]), f2bf(hv[1]), f2bf(hv[2]), f2bf(hv[3]) };
  ((u16x4*)(h2 + (size_t)t*TD))[tid] = o;

  // fp32 router logits (top-k is discrete: keep full precision)
  float acc[TE] = {0,0,0,0,0,0,0,0};
#pragma unroll
  for (int q = 0; q < 4; ++q){
    const int d = tid*4 + q;
    const float4 r0 = ((const float4*)(rw + (size_t)d*TE))[0];
    const float4 r1 = ((const float4*)(rw + (size_t)d*TE))[1];
    acc[0] += hv[q]*r0.x; acc[1] += hv[q]*r0.y; acc[2] += hv[q]*r0.z; acc[3] += hv[q]*r0.w;
    acc[4] += hv[q]*r1.x; acc[5] += hv[q]*r1.y; acc[6] += hv[q]*r1.z; acc[7] += hv[q]*r1.w;
  }
#pragma unroll
  for (int d = 32; d >= 1; d >>= 1)
#pragma unroll
    for (int e = 0; e < TE; ++e) acc[e] += __shfl_down(acc[e], d);
  __shared__ float racc[4][TE];
  if (lane == 0)
#pragma unroll
    for (int e = 0; e < TE; ++e) racc[wave][e] = acc[e];
  __syncthreads();
  if (tid == 0){
    float lg[TE];
#pragma unroll
    for (int e = 0; e < TE; ++e)
      lg[e] = racc[0][e] + racc[1][e] + racc[2][e] + racc[3][e] + rb[e];
    int e1 = 0;
    for (int e = 1; e < TE; ++e) if (lg[e] > lg[e1]) e1 = e;
    int e2 = -1;
    for (int e = 0; e < TE; ++e){ if (e == e1) continue; if (e2 < 0 || lg[e] > lg[e2]) e2 = e; }
    const float w1 = 1.f / (1.f + __expf(lg[e2] - lg[e1]));
    const float w2 = 1.f / (1.f + __expf(lg[e1] - lg[e2]));
    topidx[t*2]   = e1;  topidx[t*2+1] = e2;
    topw[t*2]     = w1;  topw[t*2+1]   = w2;
    atomicAdd(&counts[e1], 1);
    atomicAdd(&counts[e2], 1);
  }
}

__global__ void offsets_kernel(const int* __restrict__ counts, int* __restrict__ offs,
                               int* __restrict__ cursors, float* __restrict__ load_out){
  if (threadIdx.x == 0){
    int off = 0;
    for (int e = 0; e < TE; ++e){
      offs[e] = off; cursors[e] = off; off += counts[e];
      load_out[e] = (float)counts[e];
    }
  }
}

__global__ __launch_bounds__(256)
void scatter_kernel(const int* __restrict__ topidx, const float* __restrict__ topw,
                    int* __restrict__ cursors, int* __restrict__ assign_tok,
                    float* __restrict__ assign_w, int* __restrict__ token_slot){
  const int t = blockIdx.x*256 + threadIdx.x;
  if (t >= TT) return;
#pragma unroll
  for (int k = 0; k < 2; ++k){
    const int e = topidx[t*2 + k];
    const int pos = atomicAdd(&cursors[e], 1);
    assign_tok[pos] = t;
    assign_w[pos]   = topw[t*2 + k];
    token_slot[t*2 + k] = pos;
  }
}

// ---------------------------------------------------------------- GEMM core
// C[128,128] tile = A[M,K](bf16, row-major) x Bt[N,K](bf16, row-major) per block.
template<int MODE>
__global__ __launch_bounds__(256)
void gemm_bt(const u16* __restrict__ A, const u16* __restrict__ Bt,
             const float* __restrict__ bias, const float* __restrict__ resid,
             float* __restrict__ outF, u16* __restrict__ outB,
             int K, int N,
             const int* __restrict__ counts, const int* __restrict__ offs,
             const int* __restrict__ assign_tok, const float* __restrict__ assign_w)
{
  __shared__ u16 As[2][128*32];
  __shared__ u16 Bs[2][128*32];
  const int tid = threadIdx.x;
  const int n0  = blockIdx.x * 128;
  int row0 = 0, slotbase = 0, cntRem = 128, slotEnd = 0;
  if (MODE == 0 || MODE == 1){
    row0 = blockIdx.y * 128;
  } else {
    const int e  = blockIdx.y >> 5;
    const int mt = blockIdx.y & 31;
    const int cnt = counts[e];
    if (mt*128 >= cnt) return;
    slotbase = offs[e] + mt*128;
    slotEnd  = offs[e] + cnt;
    cntRem   = cnt - mt*128; if (cntRem > 128) cntRem = 128;
    Bt   += (size_t)e * K * N;
    bias += (size_t)e * N;
  }
  const int srow = tid >> 2, skseg = tid & 3;
  const u16* aptr[2];
  const u16* bptr[2];
#pragma unroll
  for (int it = 0; it < 2; ++it){
    const int r = it*64 + srow;
    if (MODE == 0 || MODE == 1){
      aptr[it] = A + (size_t)(row0 + r)*K + skseg*8;
    } else if (MODE == 2){
      int slot = slotbase + r; if (slot > slotEnd-1) slot = slotEnd-1;
      aptr[it] = A + (size_t)assign_tok[slot]*K + skseg*8;
    } else {
      int slot = slotbase + r; if (slot > slotEnd-1) slot = slotEnd-1;
      aptr[it] = A + (size_t)slot*K + skseg*8;
    }
    bptr[it] = Bt + (size_t)(n0 + it*64 + srow)*K + skseg*8;
  }

#define STAGE(buf, kt) do {                                        \
    _Pragma("unroll")                                              \
    for (int it = 0; it < 2; ++it){                                \
      GLL16(aptr[it] + (size_t)(kt)*32, &As[buf][it*2048 + tid*8]);\
      GLL16(bptr[it] + (size_t)(kt)*32, &Bs[buf][it*2048 + tid*8]);\
    } } while(0)

  const int lane = tid & 63, wave = tid >> 6;
  const int wm = (wave >> 1) * 64, wn = (wave & 1) * 64;
  const int r16 = lane & 15, kgr = lane >> 4;
  const f32x4 z4 = {0.f,0.f,0.f,0.f};
  f32x4 acc[4][4];
#pragma unroll
  for (int i = 0; i < 4; ++i)
#pragma unroll
    for (int j = 0; j < 4; ++j) acc[i][j] = z4;

  STAGE(0, 0);
  __syncthreads();
  const int nk = K >> 5;
  for (int kt = 0; kt < nk; ++kt){
    const int cur = kt & 1;
    if (kt + 1 < nk) STAGE(cur ^ 1, kt + 1);
    bf16x8 a[4], b[4];
#pragma unroll
    for (int i = 0; i < 4; ++i)
      a[i] = *(const bf16x8*)&As[cur][(wm + i*16 + r16)*32 + kgr*8];
#pragma unroll
    for (int j = 0; j < 4; ++j)
      b[j] = *(const bf16x8*)&Bs[cur][(wn + j*16 + r16)*32 + kgr*8];
#pragma unroll
    for (int i = 0; i < 4; ++i)
#pragma unroll
      for (int j = 0; j < 4; ++j)
        acc[i][j] = MFMA16(a[i], b[j], acc[i][j]);
    __syncthreads();
  }
#undef STAGE

#pragma unroll
  for (int i = 0; i < 4; ++i){
#pragma unroll
    for (int r = 0; r < 4; ++r){
      const int row = wm + i*16 + kgr*4 + r;
#pragma unroll
      for (int j = 0; j < 4; ++j){
        const int col = n0 + wn + j*16 + r16;
        float v = acc[i][j][r];
        if (MODE == 0){
          v += bias[col];
          outB[(size_t)(row0 + row)*QLD + col] = f2bf(v);
        } else if (MODE == 1){
          const size_t idx = (size_t)(row0 + row)*TD + col;
          outF[idx] = v + bias[col] + resid[idx];
        } else if (MODE == 2){
          if (row < cntRem){
            v += bias[col];
            const float t = tanhf(0.7978845608028654f * (v + 0.044715f*v*v*v));
            outB[(size_t)(slotbase + row)*TF + col] = f2bf(0.5f*v*(1.f + t));
          }
        } else {
          if (row < cntRem){
            outF[(size_t)(slotbase + row)*TD + col] =
                (v + bias[col]) * assign_w[slotbase + row];
          }
        }
      }
    }
  }
}

// ------------------------------------------------------- flash attention
// Swapped-QK^T structure: per kv-tile compute S^T = mfma(K,Q) so each lane
// owns one q-row (q = qw + (lane&15)) -> in-lane row stats + 2 shfl_xor.
// Causal pairing: block handles q-tiles (pq, 31-pq) -> constant 33 kv-tiles.
// V double-buffered in LDS (XOR-swizzled transpose), one barrier per tile,
// next V tile's global loads issued before compute (async-stage split).
__global__ __launch_bounds__(256)
void attn_kernel(const u16* __restrict__ qkv, u16* __restrict__ ctx){
  const int blk = blockIdx.x;
  const int pq = blk & 15, bh = blk >> 4;
  const int b = bh >> 4, h = bh & 15;
  const int tid = threadIdx.x, lane = tid & 63, wave = tid >> 6;
  const int r16 = lane & 15, kgr = lane >> 4;
  const size_t base = (size_t)b * TS * QLD;
  const u16* Q  = qkv + base + h*THD;
  const u16* Kp = qkv + base + TD + h*THD;
  const u16* Vp = qkv + base + 2*TD + h*THD;

  __shared__ u16 VT[2][64*64];     // V^T [hd][kv], XOR-swizzled
  __shared__ u16 Plds[4][16*64];   // per-wave P [q][kv], XOR-swizzled

  const int kvr0 = tid >> 3,          hs0 = tid & 7;        // staging coords
  const int kvr1 = (tid + 256) >> 3,  hs1 = tid & 7;
  const f32x4 z4 = {0.f,0.f,0.f,0.f};

  for (int qsel = 0; qsel < 2; ++qsel){
    const int qt = qsel ? (31 - pq) : pq;
    const int qw = qt*64 + wave*16;

    const bf16x8 qa0 = *(const bf16x8*)&Q[(size_t)(qw + r16)*QLD + kgr*8];
    const bf16x8 qa1 = *(const bf16x8*)&Q[(size_t)(qw + r16)*QLD + 32 + kgr*8];

    f32x4 O[4] = { z4, z4, z4, z4 };
    float m_r = -1e30f;     // stats live in S^T layout: q = qw + r16
    float l_r = 0.f;

    // preload V tile 0 into regs
    u16x8 v0 = *(const u16x8*)&Vp[(size_t)kvr0*QLD + hs0*8];
    u16x8 v1 = *(const u16x8*)&Vp[(size_t)kvr1*QLD + hs1*8];

    __syncthreads();   // protect VT buffers against previous qsel's readers

    for (int kt = 0; kt <= qt; ++kt){
      const int kv0 = kt*64;
      u16* vt = &VT[kt & 1][0];
      // 1. write staged V (transpose + swizzle);   2-way max on banks
#pragma unroll
      for (int jj = 0; jj < 8; ++jj)
        vt[((hs0*8 + jj)*64 + kvr0) ^ (hs0<<3)] = v0[jj];
#pragma unroll
      for (int jj = 0; jj < 8; ++jj)
        vt[((hs1*8 + jj)*64 + kvr1) ^ (hs1<<3)] = v1[jj];
      // 2. issue next V tile's loads (latency hides under this tile's compute)
      if (kt < qt){
        v0 = *(const u16x8*)&Vp[(size_t)(kv0 + 64 + kvr0)*QLD + hs0*8];
        v1 = *(const u16x8*)&Vp[(size_t)(kv0 + 64 + kvr1)*QLD + hs1*8];
      }
      // 3. S^T = K Q^T : lane holds q=qw+r16, kv = kv0 + j*16 + kgr*4 + r
      f32x4 s[4];
      __builtin_amdgcn_s_setprio(1);
#pragma unroll
      for (int j = 0; j < 4; ++j){
        const bf16x8 k0 = *(const bf16x8*)&Kp[(size_t)(kv0 + j*16 + r16)*QLD + kgr*8];
        const bf16x8 k1 = *(const bf16x8*)&Kp[(size_t)(kv0 + j*16 + r16)*QLD + 32 + kgr*8];
        s[j] = MFMA16(k0, qa0, z4);
        s[j] = MFMA16(k1, qa1, s[j]);
      }
      __builtin_amdgcn_s_setprio(0);
      // 4. online softmax, all in S^T layout
      const bool diag = (kt == qt);
      float mx = -3e38f;
#pragma unroll
      for (int j = 0; j < 4; ++j)
#pragma unroll
        for (int r = 0; r < 4; ++r){
          float v = s[j][r] * 0.125f;
          if (diag && (kv0 + j*16 + kgr*4 + r > qw + r16)) v += -1e9f;
          s[j][r] = v;
          mx = fmaxf(mx, v);
        }
      mx = fmaxf(mx, __shfl_xor(mx, 16));
      mx = fmaxf(mx, __shfl_xor(mx, 32));
      const float mn = fmaxf(m_r, mx);
      const float al = __expf(m_r - mn);
      m_r = mn;
      float rs = 0.f;
#pragma unroll
      for (int j = 0; j < 4; ++j){
        u16x4 pw;
#pragma unroll
        for (int r = 0; r < 4; ++r){
          const float p = __expf(s[j][r] - mn);
          rs += p;
          pw[r] = f2bf(p);
        }
        // 4 consecutive kv per (j): single b64 write
        *(u16x4*)&Plds[wave][(r16*64 + j*16 + kgr*4) ^ ((r16&7)<<3)] = pw;
      }
      rs += __shfl_xor(rs, 16);
      rs += __shfl_xor(rs, 32);
      l_r = l_r*al + rs;
      // alpha for O rows (O row q_local = kgr*4+r): gather from S^T layout
      float alr[4];
#pragma unroll
      for (int r = 0; r < 4; ++r)
        alr[r] = __shfl(al, (lane & 48) | (kgr*4 + r));
#pragma unroll
      for (int c = 0; c < 4; ++c)
#pragma unroll
        for (int r = 0; r < 4; ++r) O[c][r] *= alr[r];
      __syncthreads();   // VT writes visible; single barrier per tile
      // 5. O += P V
      __builtin_amdgcn_s_setprio(1);
#pragma unroll
      for (int kbl = 0; kbl < 2; ++kbl){
        const bf16x8 pa = *(const bf16x8*)&Plds[wave][(r16*64 + kbl*32 + kgr*8) ^ ((r16&7)<<3)];
#pragma unroll
        for (int c = 0; c < 4; ++c){
          const int hd = c*16 + r16;
          const bf16x8 vb = *(const bf16x8*)&vt[(hd*64 + kbl*32 + kgr*8) ^ (((hd>>3)&7)<<3)];
          O[c] = MFMA16(pa, vb, O[c]);
        }
      }
      __builtin_amdgcn_s_setprio(0);
    }
    // epilogue: redistribute l to O layout, normalize, store
    u16* cp = ctx + (size_t)b*TS*TD + h*THD;
#pragma unroll
    for (int r = 0; r < 4; ++r){
      const float lr = __shfl(l_r, (lane & 48) | (kgr*4 + r));
      const float inv = 1.f / lr;
      const int qrow = qw + kgr*4 + r;
#pragma unroll
      for (int c = 0; c < 4; ++c)
        cp[(size_t)qrow*TD + c*16 + r16] = f2bf(O[c][r] * inv);
    }
  }
}

// ---------------------------------------------------------------- combine
__global__ __launch_bounds__(256)
void combine_kernel(float* __restrict__ out, const float* __restrict__ slot_out,
                    const int* __restrict__ token_slot){
  const int i = blockIdx.x*256 + threadIdx.x;   // over TT*TD/4
  const int t = i >> 8, c = i & 255;
  const int s0 = token_slot[t*2], s1 = token_slot[t*2+1];
  const float4 a = ((const float4*)out)[i];
  const float4 u = ((const float4*)slot_out)[(size_t)s0*256 + c];
  const float4 w = ((const float4*)slot_out)[(size_t)s1*256 + c];
  float4 o = { a.x+u.x+w.x, a.y+u.y+w.y, a.z+u.z+w.z, a.w+u.w+w.w };
  ((float4*)out)[i] = o;
}

// ---------------------------------------------------------------- launcher
extern "C" void kernel_launch(void* const* d_in, const int* in_sizes, int n_in,
                              void* d_out, int out_size, void* d_ws, size_t ws_size,
                              hipStream_t stream){
  const float* x     = (const float*)d_in[0];
  const float* ln1_g = (const float*)d_in[2];
  const float* ln1_b = (const float*)d_in[3];
  const float* w_qkv = (const float*)d_in[4];
  const float* b_qkv = (const float*)d_in[5];
  const float* w_o   = (const float*)d_in[6];
  const float* b_o   = (const float*)d_in[7];
  const float* ln2_g = (const float*)d_in[8];
  const float* ln2_b = (const float*)d_in[9];
  const float* rw    = (const float*)d_in[10];
  const float* rb    = (const float*)d_in[11];
  const float* w1    = (const float*)d_in[12];
  const float* b1    = (const float*)d_in[13];
  const float* w2    = (const float*)d_in[14];
  const float* b2    = (const float*)d_in[15];
  float* out = (float*)d_out;

  char* wsp = (char*)d_ws;
  size_t off = 0;
  auto alloc = [&](size_t bytes)->void*{
    void* p = wsp + off; off += (bytes + 255) & ~(size_t)255; return p;
  };
  u16* wqkv_bf = (u16*)alloc((size_t)3*TD*TD*2);
  u16* wo_bf   = (u16*)alloc((size_t)TD*TD*2);
  u16* w1t     = (u16*)alloc((size_t)TE*TD*TF*2);   // [E][F][D]
  u16* w2t     = (u16*)alloc((size_t)TE*TD*TF*2);   // [E][D][F]
  u16* h2bf    = (u16*)alloc((size_t)TT*TD*2);
  u16* hidden  = (u16*)alloc((size_t)TT*TKK*TF*2);  // [8192][F]
  char* ph1    = (char*)alloc((size_t)44*1024*1024); // phase-1 arena / slot_out
  u16* hbf     = (u16*)ph1;
  u16* qkvbf   = (u16*)(ph1 + (size_t)TT*TD*2);
  u16* ctxbf   = (u16*)(ph1 + (size_t)TT*TD*2 + (size_t)TT*3*TD*2);
  float* slot_out = (float*)ph1;                     // reuses dead phase-1 space
  int*   topidx     = (int*)alloc(TT*2*4);
  float* topw       = (float*)alloc(TT*2*4);
  int*   counts     = (int*)alloc(64);
  int*   offs       = (int*)alloc(64);
  int*   cursors    = (int*)alloc(64);
  int*   assign_tok = (int*)alloc(TT*TKK*4);
  float* assign_w_  = (float*)alloc(TT*TKK*4);
  int*   token_slot = (int*)alloc(TT*TKK*4);
  (void)ws_size; (void)in_sizes; (void)n_in; (void)out_size;

  const dim3 b256(256);
  zero_counts_kernel<<<dim3(1), dim3(64), 0, stream>>>(counts);
  cast_bf_kernel<<<dim3(3*TD*TD/4/256), b256, 0, stream>>>(w_qkv, wqkv_bf, 3*TD*TD/4);
  cast_bf_kernel<<<dim3(TD*TD/4/256), b256, 0, stream>>>(w_o, wo_bf, TD*TD/4);
  transpose_cast_kernel<<<dim3(TF/32, TD/32, TE), b256, 0, stream>>>(w1, w1t, TD, TF);
  transpose_cast_kernel<<<dim3(TD/32, TF/32, TE), b256, 0, stream>>>(w2, w2t, TF, TD);
  ln1_kernel<<<dim3(TT), b256, 0, stream>>>(x, ln1_g, ln1_b, hbf);
  gemm_bt<0><<<dim3(3*TD/128, TT/128), b256, 0, stream>>>(
      hbf, wqkv_bf, b_qkv, nullptr, nullptr, qkvbf, TD, 3*TD,
      nullptr, nullptr, nullptr, nullptr);
  attn_kernel<<<dim3(TB*TH*16), b256, 0, stream>>>(qkvbf, ctxbf);
  gemm_bt<1><<<dim3(TD/128, TT/128), b256, 0, stream>>>(
      ctxbf, wo_bf, b_o, x, out, nullptr, TD, TD,
      nullptr, nullptr, nullptr, nullptr);
  ln2_router_kernel<<<dim3(TT), b256, 0, stream>>>(
      out, ln2_g, ln2_b, h2bf, rw, rb, counts, topidx, topw);
  offsets_kernel<<<dim3(1), dim3(64), 0, stream>>>(counts, offs, cursors, out + (size_t)TT*TD);
  scatter_kernel<<<dim3(TT/256), b256, 0, stream>>>(
      topidx, topw, cursors, assign_tok, assign_w_, token_slot);
  gemm_bt<2><<<dim3(TF/128, TE*32), b256, 0, stream>>>(
      h2bf, w1t, b1, nullptr, nullptr, hidden, TD, TF,
      counts, offs, assign_tok, assign_w_);
  gemm_bt<3><<<dim3(TD/128, TE*32), b256, 0, stream>>>(
      hidden, w2t, b2, nullptr, slot_out, nullptr, TF, TD,
      counts, offs, assign_tok, assign_w_);
  combine_kernel<<<dim3(TT*TD/4/256), b256, 0, stream>>>(out, slot_out, token_slot);
}